// Round 7
// baseline (346.312 us; speedup 1.0000x reference)
//
#include <hip/hip_runtime.h>

#define N_NODES 10000
#define N_EDGES 320000
#define E_PAD (N_EDGES + 8 * N_NODES)   // CSR padded to 8-multiples per node

// ---------------------------------------------------------------------------
// Graph preprocessing: deg/dinv + CSR-by-destination build (8-padded segments)
// ---------------------------------------------------------------------------

__global__ __launch_bounds__(256) void init_kernel(float* deg, int* counts, int* cursor, int n) {
    int i = blockIdx.x * 256 + threadIdx.x;
    if (i < n) { deg[i] = 1.0f; counts[i] = 0; cursor[i] = 0; }  // self-loop weight 1
}

__global__ __launch_bounds__(256) void zero_csr_kernel(int* __restrict__ src,
                                                       float* __restrict__ w, int n) {
    int i = blockIdx.x * 256 + threadIdx.x;
    if (i < n) { src[i] = 0; w[i] = 0.f; }   // pad edges: node 0, weight 0
}

__global__ __launch_bounds__(256) void deg_count_kernel(const int* __restrict__ col,
                                                        const float* __restrict__ ew,
                                                        float* __restrict__ deg,
                                                        int* __restrict__ counts, int e) {
    int i = blockIdx.x * 256 + threadIdx.x;
    if (i < e) {
        int c = col[i];
        atomicAdd(deg + c, ew[i]);
        atomicAdd(counts + c, 1);
    }
}

// Single-block 1024-thread exclusive scan over 8-PADDED counts + fused dinv.
// All ptr[] values are multiples of 8 -> aligned int4/float4 metadata loads.
__global__ __launch_bounds__(1024) void scan_dinv_kernel(const int* __restrict__ counts,
                                                         int* __restrict__ ptr,
                                                         const float* __restrict__ deg,
                                                         float* __restrict__ dinv, int n) {
    __shared__ int wsum[16];
    __shared__ int woff[16];
    __shared__ int carry_s, tot_s;
    const int lane = threadIdx.x & 63;
    const int wid = threadIdx.x >> 6;
    if (threadIdx.x == 0) carry_s = 0;
    __syncthreads();
    for (int base = 0; base < n; base += 1024) {
        int i = base + (int)threadIdx.x;
        int v = (i < n) ? ((counts[i] + 7) & ~7) : 0;   // pad to multiple of 8
        if (i < n) {
            float d = deg[i];
            dinv[i] = (d > 0.0f) ? rsqrtf(d) : 0.0f;
        }
        int x = v;
#pragma unroll
        for (int off = 1; off < 64; off <<= 1) {
            int t = __shfl_up(x, off);
            if (lane >= off) x += t;
        }
        if (lane == 63) wsum[wid] = x;
        __syncthreads();
        if (wid == 0) {
            int s = (lane < 16) ? wsum[lane] : 0;
            int y = s;
#pragma unroll
            for (int off = 1; off < 16; off <<= 1) {
                int t = __shfl_up(y, off);
                if (lane >= off) y += t;
            }
            if (lane < 16) woff[lane] = y - s;
            if (lane == 15) tot_s = y;
        }
        __syncthreads();
        int carry = carry_s;
        if (i < n) ptr[i] = carry + woff[wid] + x - v;
        __syncthreads();
        if (threadIdx.x == 0) carry_s = carry + tot_s;
        __syncthreads();
    }
    if (threadIdx.x == 0) ptr[n] = carry_s;
}

__global__ __launch_bounds__(256) void scatter_kernel(const int* __restrict__ row,
                                                      const int* __restrict__ col,
                                                      const float* __restrict__ ew,
                                                      const float* __restrict__ dinv,
                                                      const int* __restrict__ ptr,
                                                      int* __restrict__ cursor,
                                                      int* __restrict__ csr_src,
                                                      float* __restrict__ csr_w, int e) {
    int i = blockIdx.x * 256 + threadIdx.x;
    if (i < e) {
        int c = col[i], r = row[i];
        int pos = ptr[c] + atomicAdd(cursor + c, 1);
        csr_src[pos] = r;
        csr_w[pos] = dinv[r] * ew[i] * dinv[c];
    }
}

// ---------------------------------------------------------------------------
// bf16 split helpers (RNE)
// ---------------------------------------------------------------------------
__device__ __forceinline__ unsigned short f2bf_rne(float v) {
    unsigned int u = __float_as_uint(v);
    return (unsigned short)((u + 0x7FFFu + ((u >> 16) & 1u)) >> 16);
}
__device__ __forceinline__ float bf2f(unsigned short h) {
    return __uint_as_float(((unsigned int)h) << 16);
}

// ---------------------------------------------------------------------------
// XCD-sliced aggregation, split-bf16 output, 8-padded edge segments:
//   acc[n,f] = dinv[n]^2 * x[n,f] + sum_in w * x[src,f]   (fp32)
// 128 threads = 2 waves = 2 nodes, same 64-feature slice.
// slice = blockIdx.x & mask keeps each XCD on ONE 2.56 MB activation slab.
// Metadata via wave-uniform int4/float4 broadcasts: 1.5 VMEM issues/edge.
// ---------------------------------------------------------------------------
__global__ __launch_bounds__(128) void agg_slice_kernel(const float* __restrict__ x,
                                                        const int* __restrict__ ptr,
                                                        const int* __restrict__ csr_src,
                                                        const float* __restrict__ csr_w,
                                                        const float* __restrict__ dinv,
                                                        unsigned short* __restrict__ ohi,
                                                        unsigned short* __restrict__ olo,
                                                        int F, int slice_mask, int slice_shift) {
    const int b = blockIdx.x;
    const int slice = b & slice_mask;
    const int wave = (int)threadIdx.x >> 6;
    const int lane = (int)threadIdx.x & 63;
    const int node = (b >> slice_shift) * 2 + wave;
    const int f = slice * 64 + lane;
    const float di = dinv[node];
    const float si = di * di;
    float acc = si * x[(size_t)node * F + f];
    const int s = ptr[node], e = ptr[node + 1];   // 8-aligned, length % 8 == 0

    for (int j = s; j < e; j += 8) {
        int4   i0 = *(const int4*)(csr_src + j);
        int4   i1 = *(const int4*)(csr_src + j + 4);
        float4 w0 = *(const float4*)(csr_w + j);
        float4 w1 = *(const float4*)(csr_w + j + 4);
        float g0 = x[(size_t)i0.x * F + f];
        float g1 = x[(size_t)i0.y * F + f];
        float g2 = x[(size_t)i0.z * F + f];
        float g3 = x[(size_t)i0.w * F + f];
        float g4 = x[(size_t)i1.x * F + f];
        float g5 = x[(size_t)i1.y * F + f];
        float g6 = x[(size_t)i1.z * F + f];
        float g7 = x[(size_t)i1.w * F + f];
        acc += w0.x * g0 + w0.y * g1 + w0.z * g2 + w0.w * g3;
        acc += w1.x * g4 + w1.y * g5 + w1.z * g6 + w1.w * g7;
    }

    unsigned short h = f2bf_rne(acc);
    float r = acc - bf2f(h);
    ohi[(size_t)node * F + f] = h;
    olo[(size_t)node * F + f] = f2bf_rne(r);
}

// Convert+transpose BOTH weight matrices in one launch:
// W [K][N] fp32 -> Wt_hi/Wt_lo [N][K] bf16.
__global__ __launch_bounds__(256) void convert_wt2_kernel(
        const float* __restrict__ W1, unsigned short* __restrict__ h1,
        unsigned short* __restrict__ l1, int K1, int N1,
        const float* __restrict__ W2, unsigned short* __restrict__ h2,
        unsigned short* __restrict__ l2, int K2, int N2) {
    int idx = blockIdx.x * 256 + threadIdx.x;
    const int n1 = K1 * N1;
    const float* W; unsigned short *hi, *lo; int K, N;
    if (idx < n1) { W = W1; hi = h1; lo = l1; K = K1; N = N1; }
    else {
        idx -= n1;
        if (idx >= K2 * N2) return;
        W = W2; hi = h2; lo = l2; K = K2; N = N2;
    }
    int k = idx / N, n = idx - k * N;
    float v = W[idx];
    unsigned short h = f2bf_rne(v);
    float r = v - bf2f(h);
    hi[(size_t)n * K + k] = h;
    lo[(size_t)n * K + k] = f2bf_rne(r);
}

// ---------------------------------------------------------------------------
// Split-bf16 MFMA GEMM + bias (+relu), async global->LDS staging.
//   C[M,N] = (Ahi+Alo)[M,K] @ (Bhi+Blo)[K,N] + bias   (lo*lo dropped)
// B transposed as Bt[N][K]; A row-padded to TM multiple (pad rows discarded).
// Tile 128m x 128n, BK=32, 256 threads = 4 waves of 64m x 64n.
// LDS: unpadded [row][32 bf16] blocks, XOR chunk swizzle (2-way alias, free).
// ---------------------------------------------------------------------------
typedef short bf16x8 __attribute__((ext_vector_type(8)));
typedef float f32x4 __attribute__((ext_vector_type(4)));

#define TM 128
#define TN 128
#define BK 32
#define LDS_A_HI 0
#define LDS_A_LO 8192
#define LDS_B_HI 16384
#define LDS_B_LO 24576
#define LDS_BUF  32768

__device__ __forceinline__ void async16(const unsigned short* g, unsigned char* l) {
    __builtin_amdgcn_global_load_lds(
        (const __attribute__((address_space(1))) unsigned int*)g,
        (__attribute__((address_space(3))) unsigned int*)l, 16, 0, 0);
}

__global__ __launch_bounds__(256, 2) void gemm_mfma_kernel(
        const unsigned short* __restrict__ Ahi,
        const unsigned short* __restrict__ Alo,
        const unsigned short* __restrict__ Bthi,
        const unsigned short* __restrict__ Btlo,
        const float* __restrict__ bias,
        float* __restrict__ C,
        int M, int K, int N, int relu) {
    __shared__ unsigned char lds[2 * LDS_BUF];
    const int t = (int)threadIdx.x;
    const int bm = blockIdx.y * TM;
    const int bn = blockIdx.x * TN;
    const int lane = t & 63;
    const int wave = t >> 6;
    const int wm = (wave & 1) * 64;
    const int wn = (wave >> 1) * 64;

    // ---- staging geometry (per lane): 16-row blocks, 1024 B per async issue ----
    const int slr = lane >> 2;                       // 0..15 local row
    const int scc = (lane & 3) ^ ((slr >> 1) & 3);   // swizzled global chunk
    const int bi0 = wave * 2, bi1 = wave * 2 + 1;    // 16-row block ids (0..7)
    const unsigned short* gA0h = Ahi + (size_t)(bm + bi0 * 16 + slr) * K + scc * 8;
    const unsigned short* gA1h = Ahi + (size_t)(bm + bi1 * 16 + slr) * K + scc * 8;
    const unsigned short* gA0l = Alo + (size_t)(bm + bi0 * 16 + slr) * K + scc * 8;
    const unsigned short* gA1l = Alo + (size_t)(bm + bi1 * 16 + slr) * K + scc * 8;
    const unsigned short* gB0h = Bthi + (size_t)(bn + bi0 * 16 + slr) * K + scc * 8;
    const unsigned short* gB1h = Bthi + (size_t)(bn + bi1 * 16 + slr) * K + scc * 8;
    const unsigned short* gB0l = Btlo + (size_t)(bn + bi0 * 16 + slr) * K + scc * 8;
    const unsigned short* gB1l = Btlo + (size_t)(bn + bi1 * 16 + slr) * K + scc * 8;

    // ---- fragment read geometry ----
    const int quad = lane >> 4;
    const int lr16 = lane & 15;
    const int fs = (quad ^ ((lr16 >> 1) & 3)) * 16;  // swizzled slot byte offset

    f32x4 acc[4][4];
    const f32x4 zero4 = {0.f, 0.f, 0.f, 0.f};
#pragma unroll
    for (int i = 0; i < 4; ++i)
#pragma unroll
        for (int j = 0; j < 4; ++j) acc[i][j] = zero4;

    const int KT = K / BK;

    auto stage = [&](int kt, int buf) {
        const int k0 = kt * BK;
        unsigned char* b = &lds[buf * LDS_BUF];
        async16(gA0h + k0, b + LDS_A_HI + bi0 * 1024);
        async16(gA1h + k0, b + LDS_A_HI + bi1 * 1024);
        async16(gA0l + k0, b + LDS_A_LO + bi0 * 1024);
        async16(gA1l + k0, b + LDS_A_LO + bi1 * 1024);
        async16(gB0h + k0, b + LDS_B_HI + bi0 * 1024);
        async16(gB1h + k0, b + LDS_B_HI + bi1 * 1024);
        async16(gB0l + k0, b + LDS_B_LO + bi0 * 1024);
        async16(gB1l + k0, b + LDS_B_LO + bi1 * 1024);
    };

    stage(0, 0);
    __syncthreads();

    for (int kt = 0; kt < KT; ++kt) {
        const int buf = kt & 1;
        if (kt + 1 < KT) stage(kt + 1, buf ^ 1);   // async, drains at barrier below

        unsigned char* b = &lds[buf * LDS_BUF];
        bf16x8 ah[4], al[4], bh[4], bl[4];
#pragma unroll
        for (int i = 0; i < 4; ++i) {
            int ro = (wm + i * 16 + lr16) * 64 + fs;
            ah[i] = *(const bf16x8*)(b + LDS_A_HI + ro);
            al[i] = *(const bf16x8*)(b + LDS_A_LO + ro);
        }
#pragma unroll
        for (int j = 0; j < 4; ++j) {
            int ro = (wn + j * 16 + lr16) * 64 + fs;
            bh[j] = *(const bf16x8*)(b + LDS_B_HI + ro);
            bl[j] = *(const bf16x8*)(b + LDS_B_LO + ro);
        }
#pragma unroll
        for (int i = 0; i < 4; ++i)
#pragma unroll
            for (int j = 0; j < 4; ++j) {
                acc[i][j] = __builtin_amdgcn_mfma_f32_16x16x32_bf16(ah[i], bh[j], acc[i][j], 0, 0, 0);
                acc[i][j] = __builtin_amdgcn_mfma_f32_16x16x32_bf16(ah[i], bl[j], acc[i][j], 0, 0, 0);
                acc[i][j] = __builtin_amdgcn_mfma_f32_16x16x32_bf16(al[i], bh[j], acc[i][j], 0, 0, 0);
            }
        __syncthreads();
    }

    // epilogue: bias (+relu), store fp32
    float bcol[4];
#pragma unroll
    for (int j = 0; j < 4; ++j) bcol[j] = bias[bn + wn + j * 16 + lr16];
#pragma unroll
    for (int i = 0; i < 4; ++i) {
#pragma unroll
        for (int r = 0; r < 4; ++r) {
            int m = bm + wm + i * 16 + quad * 4 + r;
            if (m < M) {
#pragma unroll
                for (int j = 0; j < 4; ++j) {
                    float vv = acc[i][j][r] + bcol[j];
                    if (relu) vv = fmaxf(vv, 0.f);
                    C[(size_t)m * N + bn + wn + j * 16 + lr16] = vv;
                }
            }
        }
    }
}

// ---------------------------------------------------------------------------
// GEMM for layer 3: N=8, K=768.  One wave per row; float4 A loads (3 iters).
// ---------------------------------------------------------------------------
__global__ __launch_bounds__(64) void gemm_n8_kernel(const float* __restrict__ A,
                                                     const float* __restrict__ B,
                                                     float* __restrict__ C, int K) {
    int m = blockIdx.x;
    int lane = threadIdx.x;
    const float* a = A + (size_t)m * K;
    float acc[8] = {};
    for (int k = lane * 4; k < K; k += 256) {
        float4 a4 = *(const float4*)(a + k);
        const float aq[4] = {a4.x, a4.y, a4.z, a4.w};
#pragma unroll
        for (int q = 0; q < 4; ++q) {
            float4 b0 = *(const float4*)(B + (size_t)(k + q) * 8);
            float4 b1 = *(const float4*)(B + (size_t)(k + q) * 8 + 4);
            acc[0] += aq[q] * b0.x; acc[1] += aq[q] * b0.y;
            acc[2] += aq[q] * b0.z; acc[3] += aq[q] * b0.w;
            acc[4] += aq[q] * b1.x; acc[5] += aq[q] * b1.y;
            acc[6] += aq[q] * b1.z; acc[7] += aq[q] * b1.w;
        }
    }
#pragma unroll
    for (int off = 32; off > 0; off >>= 1) {
#pragma unroll
        for (int i = 0; i < 8; ++i) acc[i] += __shfl_down(acc[i], off);
    }
    if (lane == 0) {
#pragma unroll
        for (int i = 0; i < 8; ++i) C[(size_t)m * 8 + i] = acc[i];
    }
}

// Aggregation for fout=8 (final layer, +bias): one wave per node, lanes split edges.
// Padded edges (w=0, src=0) contribute nothing. xw8 is 320 KB -> L2-resident.
__global__ __launch_bounds__(64) void agg8_kernel(const float* __restrict__ xw,
                                                  const int* __restrict__ ptr,
                                                  const int* __restrict__ csr_src,
                                                  const float* __restrict__ csr_w,
                                                  const float* __restrict__ dinv,
                                                  const float* __restrict__ bias,
                                                  float* __restrict__ out) {
    int node = blockIdx.x;
    int lane = threadIdx.x;
    float acc[8] = {};
    int s = ptr[node], e = ptr[node + 1];
    for (int j = s + lane; j < e; j += 64) {
        int src = csr_src[j];
        float w = csr_w[j];
        float4 g0 = *(const float4*)(xw + (size_t)src * 8);
        float4 g1 = *(const float4*)(xw + (size_t)src * 8 + 4);
        acc[0] += w * g0.x; acc[1] += w * g0.y; acc[2] += w * g0.z; acc[3] += w * g0.w;
        acc[4] += w * g1.x; acc[5] += w * g1.y; acc[6] += w * g1.z; acc[7] += w * g1.w;
    }
#pragma unroll
    for (int off = 32; off > 0; off >>= 1) {
#pragma unroll
        for (int i = 0; i < 8; ++i) acc[i] += __shfl_down(acc[i], off);
    }
    if (lane == 0) {
        float di = dinv[node];
        float si = di * di;
#pragma unroll
        for (int i = 0; i < 8; ++i)
            out[(size_t)node * 8 + i] = acc[i] + si * xw[(size_t)node * 8 + i] + bias[i];
    }
}

// ---------------------------------------------------------------------------

extern "C" void kernel_launch(void* const* d_in, const int* in_sizes, int n_in,
                              void* d_out, int out_size, void* d_ws, size_t ws_size,
                              hipStream_t stream) {
    const int N = N_NODES, E = N_EDGES;
    const int N_PAD = ((N + TM - 1) / TM) * TM;   // 10112
    const float* x   = (const float*)d_in[0];
    const int*   ei  = (const int*)d_in[1];   // [2, E] (row=source, col=target)
    const float* ew  = (const float*)d_in[2];
    const float* W1  = (const float*)d_in[3];
    const float* b1  = (const float*)d_in[4];
    const float* W2  = (const float*)d_in[5];
    const float* b2  = (const float*)d_in[6];
    const float* W3  = (const float*)d_in[7];
    const float* b3  = (const float*)d_in[8];
    float* out = (float*)d_out;

    const int* row = ei;        // source
    const int* col = ei + E;    // target

    // workspace layout (256B-aligned); ~59 MB total
    char* ws = (char*)d_ws;
    size_t off = 0;
    auto alloc = [&](size_t bytes) {
        void* p = ws + off;
        off += (bytes + 255) & ~(size_t)255;
        return p;
    };
    float*          deg     = (float*)alloc((size_t)N * 4);
    float*          dinv    = (float*)alloc((size_t)N * 4);
    int*            counts  = (int*)alloc((size_t)N * 4);
    int*            cursor  = (int*)alloc((size_t)N * 4);
    int*            col_ptr = (int*)alloc((size_t)(N + 1) * 4);
    int*            csr_src = (int*)alloc((size_t)E_PAD * 4);
    float*          csr_w   = (float*)alloc((size_t)E_PAD * 4);
    float*          bufF    = (float*)alloc((size_t)N * 768 * 4);       // fp32 activations
    unsigned short* Ahi     = (unsigned short*)alloc((size_t)N_PAD * 512 * 2);
    unsigned short* Alo     = (unsigned short*)alloc((size_t)N_PAD * 512 * 2);
    unsigned short* W1thi   = (unsigned short*)alloc((size_t)512 * 256 * 2);
    unsigned short* W1tlo   = (unsigned short*)alloc((size_t)512 * 256 * 2);
    unsigned short* W2thi   = (unsigned short*)alloc((size_t)768 * 512 * 2);
    unsigned short* W2tlo   = (unsigned short*)alloc((size_t)768 * 512 * 2);
    float*          xw8     = (float*)alloc((size_t)N * 8 * 4);
    (void)ws_size;

    int nb_nodes = (N + 255) / 256;
    int nb_edges = (E + 255) / 256;

    // --- graph preprocessing (once; shared by all 3 layers) ---
    init_kernel<<<nb_nodes, 256, 0, stream>>>(deg, counts, cursor, N);
    zero_csr_kernel<<<(E_PAD + 255) / 256, 256, 0, stream>>>(csr_src, csr_w, E_PAD);
    deg_count_kernel<<<nb_edges, 256, 0, stream>>>(col, ew, deg, counts, E);
    scan_dinv_kernel<<<1, 1024, 0, stream>>>(counts, col_ptr, deg, dinv, N);
    scatter_kernel<<<nb_edges, 256, 0, stream>>>(row, col, ew, dinv, col_ptr, cursor,
                                                 csr_src, csr_w, E);

    // --- weight conversion (bf16 hi/lo, transposed), single launch ---
    {
        int tot = 256 * 512 + 512 * 768;
        convert_wt2_kernel<<<(tot + 255) / 256, 256, 0, stream>>>(
            W1, W1thi, W1tlo, 256, 512, W2, W2thi, W2tlo, 512, 768);
    }

    // --- layer 1: agg(256, 4 slices) -> mfma gemm 256->512 (+b1, relu) ---
    agg_slice_kernel<<<(N / 2) * 4, 128, 0, stream>>>(x, col_ptr, csr_src, csr_w, dinv,
                                                      Ahi, Alo, 256, 3, 2);
    {
        dim3 grid(512 / TN, N_PAD / TM);
        gemm_mfma_kernel<<<grid, 256, 0, stream>>>(Ahi, Alo, W1thi, W1tlo, b1, bufF,
                                                   N, 256, 512, 1);
    }
    // --- layer 2: agg(512, 8 slices) -> mfma gemm 512->768 (+b2, relu) ---
    agg_slice_kernel<<<(N / 2) * 8, 128, 0, stream>>>(bufF, col_ptr, csr_src, csr_w, dinv,
                                                      Ahi, Alo, 512, 7, 3);
    {
        dim3 grid(768 / TN, N_PAD / TM);
        gemm_mfma_kernel<<<grid, 256, 0, stream>>>(Ahi, Alo, W2thi, W2tlo, b2, bufF,
                                                   N, 512, 768, 1);
    }
    // --- layer 3: gemm 768->8 -> agg8 (+b3) ---
    gemm_n8_kernel<<<N, 64, 0, stream>>>(bufF, W3, xw8, 768);
    agg8_kernel<<<N, 64, 0, stream>>>(xw8, col_ptr, csr_src, csr_w, dinv, b3, out);

    (void)out_size; (void)n_in; (void)in_sizes;
}

// Round 8
// 300.899 us; speedup vs baseline: 1.1509x; 1.1509x over previous
//
#include <hip/hip_runtime.h>

#define N_NODES 10000
#define N_EDGES 320000
#define E_PAD (N_EDGES + 8 * N_NODES)   // CSR padded to 8-multiples per node

// ---------------------------------------------------------------------------
// Graph preprocessing: deg/dinv + CSR-by-destination build (8-padded segments)
// ---------------------------------------------------------------------------

__global__ __launch_bounds__(256) void init_kernel(float* deg, int* counts, int* cursor, int n) {
    int i = blockIdx.x * 256 + threadIdx.x;
    if (i < n) { deg[i] = 1.0f; counts[i] = 0; cursor[i] = 0; }  // self-loop weight 1
}

__global__ __launch_bounds__(256) void zero_csr_kernel(int* __restrict__ src,
                                                       float* __restrict__ w, int n) {
    int i = blockIdx.x * 256 + threadIdx.x;
    if (i < n) { src[i] = 0; w[i] = 0.f; }   // pad edges: node 0, weight 0
}

__global__ __launch_bounds__(256) void deg_count_kernel(const int* __restrict__ col,
                                                        const float* __restrict__ ew,
                                                        float* __restrict__ deg,
                                                        int* __restrict__ counts, int e) {
    int i = blockIdx.x * 256 + threadIdx.x;
    if (i < e) {
        int c = col[i];
        atomicAdd(deg + c, ew[i]);
        atomicAdd(counts + c, 1);
    }
}

// Single-block 1024-thread exclusive scan over 8-PADDED counts + fused dinv.
__global__ __launch_bounds__(1024) void scan_dinv_kernel(const int* __restrict__ counts,
                                                         int* __restrict__ ptr,
                                                         const float* __restrict__ deg,
                                                         float* __restrict__ dinv, int n) {
    __shared__ int wsum[16];
    __shared__ int woff[16];
    __shared__ int carry_s, tot_s;
    const int lane = threadIdx.x & 63;
    const int wid = threadIdx.x >> 6;
    if (threadIdx.x == 0) carry_s = 0;
    __syncthreads();
    for (int base = 0; base < n; base += 1024) {
        int i = base + (int)threadIdx.x;
        int v = (i < n) ? ((counts[i] + 7) & ~7) : 0;   // pad to multiple of 8
        if (i < n) {
            float d = deg[i];
            dinv[i] = (d > 0.0f) ? rsqrtf(d) : 0.0f;
        }
        int x = v;
#pragma unroll
        for (int off = 1; off < 64; off <<= 1) {
            int t = __shfl_up(x, off);
            if (lane >= off) x += t;
        }
        if (lane == 63) wsum[wid] = x;
        __syncthreads();
        if (wid == 0) {
            int s = (lane < 16) ? wsum[lane] : 0;
            int y = s;
#pragma unroll
            for (int off = 1; off < 16; off <<= 1) {
                int t = __shfl_up(y, off);
                if (lane >= off) y += t;
            }
            if (lane < 16) woff[lane] = y - s;
            if (lane == 15) tot_s = y;
        }
        __syncthreads();
        int carry = carry_s;
        if (i < n) ptr[i] = carry + woff[wid] + x - v;
        __syncthreads();
        if (threadIdx.x == 0) carry_s = carry + tot_s;
        __syncthreads();
    }
    if (threadIdx.x == 0) ptr[n] = carry_s;
}

__global__ __launch_bounds__(256) void scatter_kernel(const int* __restrict__ row,
                                                      const int* __restrict__ col,
                                                      const float* __restrict__ ew,
                                                      const float* __restrict__ dinv,
                                                      const int* __restrict__ ptr,
                                                      int* __restrict__ cursor,
                                                      int* __restrict__ csr_src,
                                                      float* __restrict__ csr_w, int e) {
    int i = blockIdx.x * 256 + threadIdx.x;
    if (i < e) {
        int c = col[i], r = row[i];
        int pos = ptr[c] + atomicAdd(cursor + c, 1);
        csr_src[pos] = r;
        csr_w[pos] = dinv[r] * ew[i] * dinv[c];
    }
}

// ---------------------------------------------------------------------------
// bf16 split helpers (RNE)
// ---------------------------------------------------------------------------
__device__ __forceinline__ unsigned short f2bf_rne(float v) {
    unsigned int u = __float_as_uint(v);
    return (unsigned short)((u + 0x7FFFu + ((u >> 16) & 1u)) >> 16);
}
__device__ __forceinline__ float bf2f(unsigned short h) {
    return __uint_as_float(((unsigned int)h) << 16);
}

// ---------------------------------------------------------------------------
// XCD-sliced aggregation, split-bf16 output, 8-padded edge segments:
//   acc[n,f] = dinv[n]^2 * x[n,f] + sum_in w * x[src,f]   (fp32)
// ONE WAVE PER BLOCK; node = blockIdx>>shift is UNIFORM -> compiler
// scalarizes edge metadata (s_load) and gather bases (s_mul/s_add); the
// vector pipes pay only 1 gather + 1 v_fmac per edge.  [R7 post-mortem:
// deriving node from threadIdx made everything divergent -> 4x VALU.]
// F is a template constant -> 32-bit strength-reduced addressing.
// slice = blockIdx & mask keeps each XCD on ONE 2.56 MB activation slab.
// ---------------------------------------------------------------------------
template <int F, int SLICE_SHIFT>
__global__ __launch_bounds__(64) void agg_slice_kernel(const float* __restrict__ x,
                                                       const int* __restrict__ ptr,
                                                       const int* __restrict__ csr_src,
                                                       const float* __restrict__ csr_w,
                                                       const float* __restrict__ dinv,
                                                       unsigned short* __restrict__ ohi,
                                                       unsigned short* __restrict__ olo) {
    const int b = blockIdx.x;
    const int slice = b & ((1 << SLICE_SHIFT) - 1);
    const int node = b >> SLICE_SHIFT;           // uniform
    const int f = slice * 64 + (int)threadIdx.x;
    const float di = dinv[node];
    const float si = di * di;
    float acc = si * x[node * F + f];
    const int s = ptr[node], e = ptr[node + 1];  // 8-aligned, length % 8 == 0

    for (int j = s; j < e; j += 8) {
        // uniform indices -> scalar loads; weights land in SGPRs
        int s0 = csr_src[j + 0], s1 = csr_src[j + 1], s2 = csr_src[j + 2], s3 = csr_src[j + 3];
        int s4 = csr_src[j + 4], s5 = csr_src[j + 5], s6 = csr_src[j + 6], s7 = csr_src[j + 7];
        float w0 = csr_w[j + 0], w1 = csr_w[j + 1], w2 = csr_w[j + 2], w3 = csr_w[j + 3];
        float w4 = csr_w[j + 4], w5 = csr_w[j + 5], w6 = csr_w[j + 6], w7 = csr_w[j + 7];
        // 8 independent gathers in flight (32-bit offsets, scalar bases)
        float g0 = x[s0 * F + f];
        float g1 = x[s1 * F + f];
        float g2 = x[s2 * F + f];
        float g3 = x[s3 * F + f];
        float g4 = x[s4 * F + f];
        float g5 = x[s5 * F + f];
        float g6 = x[s6 * F + f];
        float g7 = x[s7 * F + f];
        acc += w0 * g0 + w1 * g1 + w2 * g2 + w3 * g3;
        acc += w4 * g4 + w5 * g5 + w6 * g6 + w7 * g7;
    }

    unsigned short h = f2bf_rne(acc);
    float r = acc - bf2f(h);
    ohi[node * F + f] = h;
    olo[node * F + f] = f2bf_rne(r);
}

// Convert+transpose BOTH weight matrices in one launch:
// W [K][N] fp32 -> Wt_hi/Wt_lo [N][K] bf16.
__global__ __launch_bounds__(256) void convert_wt2_kernel(
        const float* __restrict__ W1, unsigned short* __restrict__ h1,
        unsigned short* __restrict__ l1, int K1, int N1,
        const float* __restrict__ W2, unsigned short* __restrict__ h2,
        unsigned short* __restrict__ l2, int K2, int N2) {
    int idx = blockIdx.x * 256 + threadIdx.x;
    const int n1 = K1 * N1;
    const float* W; unsigned short *hi, *lo; int K, N;
    if (idx < n1) { W = W1; hi = h1; lo = l1; K = K1; N = N1; }
    else {
        idx -= n1;
        if (idx >= K2 * N2) return;
        W = W2; hi = h2; lo = l2; K = K2; N = N2;
    }
    int k = idx / N, n = idx - k * N;
    float v = W[idx];
    unsigned short h = f2bf_rne(v);
    float r = v - bf2f(h);
    hi[(size_t)n * K + k] = h;
    lo[(size_t)n * K + k] = f2bf_rne(r);
}

// ---------------------------------------------------------------------------
// Split-bf16 MFMA GEMM + bias (+relu), async global->LDS staging.
//   C[M,N] = (Ahi+Alo)[M,K] @ (Bhi+Blo)[K,N] + bias   (lo*lo dropped)
// B transposed as Bt[N][K]; A row-padded to TM multiple (pad rows discarded).
// Tile 128m x 128n, BK=32, 256 threads = 4 waves of 64m x 64n.
// LDS: unpadded [row][32 bf16] blocks, XOR chunk swizzle (2-way alias, free).
// ---------------------------------------------------------------------------
typedef short bf16x8 __attribute__((ext_vector_type(8)));
typedef float f32x4 __attribute__((ext_vector_type(4)));

#define TM 128
#define TN 128
#define BK 32
#define LDS_A_HI 0
#define LDS_A_LO 8192
#define LDS_B_HI 16384
#define LDS_B_LO 24576
#define LDS_BUF  32768

__device__ __forceinline__ void async16(const unsigned short* g, unsigned char* l) {
    __builtin_amdgcn_global_load_lds(
        (const __attribute__((address_space(1))) unsigned int*)g,
        (__attribute__((address_space(3))) unsigned int*)l, 16, 0, 0);
}

__global__ __launch_bounds__(256, 2) void gemm_mfma_kernel(
        const unsigned short* __restrict__ Ahi,
        const unsigned short* __restrict__ Alo,
        const unsigned short* __restrict__ Bthi,
        const unsigned short* __restrict__ Btlo,
        const float* __restrict__ bias,
        float* __restrict__ C,
        int M, int K, int N, int relu) {
    __shared__ unsigned char lds[2 * LDS_BUF];
    const int t = (int)threadIdx.x;
    const int bm = blockIdx.y * TM;
    const int bn = blockIdx.x * TN;
    const int lane = t & 63;
    const int wave = t >> 6;
    const int wm = (wave & 1) * 64;
    const int wn = (wave >> 1) * 64;

    // ---- staging geometry (per lane): 16-row blocks, 1024 B per async issue ----
    const int slr = lane >> 2;                       // 0..15 local row
    const int scc = (lane & 3) ^ ((slr >> 1) & 3);   // swizzled global chunk
    const int bi0 = wave * 2, bi1 = wave * 2 + 1;    // 16-row block ids (0..7)
    const unsigned short* gA0h = Ahi + (size_t)(bm + bi0 * 16 + slr) * K + scc * 8;
    const unsigned short* gA1h = Ahi + (size_t)(bm + bi1 * 16 + slr) * K + scc * 8;
    const unsigned short* gA0l = Alo + (size_t)(bm + bi0 * 16 + slr) * K + scc * 8;
    const unsigned short* gA1l = Alo + (size_t)(bm + bi1 * 16 + slr) * K + scc * 8;
    const unsigned short* gB0h = Bthi + (size_t)(bn + bi0 * 16 + slr) * K + scc * 8;
    const unsigned short* gB1h = Bthi + (size_t)(bn + bi1 * 16 + slr) * K + scc * 8;
    const unsigned short* gB0l = Btlo + (size_t)(bn + bi0 * 16 + slr) * K + scc * 8;
    const unsigned short* gB1l = Btlo + (size_t)(bn + bi1 * 16 + slr) * K + scc * 8;

    // ---- fragment read geometry ----
    const int quad = lane >> 4;
    const int lr16 = lane & 15;
    const int fs = (quad ^ ((lr16 >> 1) & 3)) * 16;  // swizzled slot byte offset

    f32x4 acc[4][4];
    const f32x4 zero4 = {0.f, 0.f, 0.f, 0.f};
#pragma unroll
    for (int i = 0; i < 4; ++i)
#pragma unroll
        for (int j = 0; j < 4; ++j) acc[i][j] = zero4;

    const int KT = K / BK;

    auto stage = [&](int kt, int buf) {
        const int k0 = kt * BK;
        unsigned char* b = &lds[buf * LDS_BUF];
        async16(gA0h + k0, b + LDS_A_HI + bi0 * 1024);
        async16(gA1h + k0, b + LDS_A_HI + bi1 * 1024);
        async16(gA0l + k0, b + LDS_A_LO + bi0 * 1024);
        async16(gA1l + k0, b + LDS_A_LO + bi1 * 1024);
        async16(gB0h + k0, b + LDS_B_HI + bi0 * 1024);
        async16(gB1h + k0, b + LDS_B_HI + bi1 * 1024);
        async16(gB0l + k0, b + LDS_B_LO + bi0 * 1024);
        async16(gB1l + k0, b + LDS_B_LO + bi1 * 1024);
    };

    stage(0, 0);
    __syncthreads();

    for (int kt = 0; kt < KT; ++kt) {
        const int buf = kt & 1;
        if (kt + 1 < KT) stage(kt + 1, buf ^ 1);   // async, drains at barrier below

        unsigned char* b = &lds[buf * LDS_BUF];
        bf16x8 ah[4], al[4], bh[4], bl[4];
#pragma unroll
        for (int i = 0; i < 4; ++i) {
            int ro = (wm + i * 16 + lr16) * 64 + fs;
            ah[i] = *(const bf16x8*)(b + LDS_A_HI + ro);
            al[i] = *(const bf16x8*)(b + LDS_A_LO + ro);
        }
#pragma unroll
        for (int j = 0; j < 4; ++j) {
            int ro = (wn + j * 16 + lr16) * 64 + fs;
            bh[j] = *(const bf16x8*)(b + LDS_B_HI + ro);
            bl[j] = *(const bf16x8*)(b + LDS_B_LO + ro);
        }
#pragma unroll
        for (int i = 0; i < 4; ++i)
#pragma unroll
            for (int j = 0; j < 4; ++j) {
                acc[i][j] = __builtin_amdgcn_mfma_f32_16x16x32_bf16(ah[i], bh[j], acc[i][j], 0, 0, 0);
                acc[i][j] = __builtin_amdgcn_mfma_f32_16x16x32_bf16(ah[i], bl[j], acc[i][j], 0, 0, 0);
                acc[i][j] = __builtin_amdgcn_mfma_f32_16x16x32_bf16(al[i], bh[j], acc[i][j], 0, 0, 0);
            }
        __syncthreads();
    }

    // epilogue: bias (+relu), store fp32
    float bcol[4];
#pragma unroll
    for (int j = 0; j < 4; ++j) bcol[j] = bias[bn + wn + j * 16 + lr16];
#pragma unroll
    for (int i = 0; i < 4; ++i) {
#pragma unroll
        for (int r = 0; r < 4; ++r) {
            int m = bm + wm + i * 16 + quad * 4 + r;
            if (m < M) {
#pragma unroll
                for (int j = 0; j < 4; ++j) {
                    float vv = acc[i][j][r] + bcol[j];
                    if (relu) vv = fmaxf(vv, 0.f);
                    C[(size_t)m * N + bn + wn + j * 16 + lr16] = vv;
                }
            }
        }
    }
}

// ---------------------------------------------------------------------------
// GEMM for layer 3: N=8, K=768.  One wave per row; float4 A loads (3 iters).
// ---------------------------------------------------------------------------
__global__ __launch_bounds__(64) void gemm_n8_kernel(const float* __restrict__ A,
                                                     const float* __restrict__ B,
                                                     float* __restrict__ C, int K) {
    int m = blockIdx.x;
    int lane = threadIdx.x;
    const float* a = A + (size_t)m * K;
    float acc[8] = {};
    for (int k = lane * 4; k < K; k += 256) {
        float4 a4 = *(const float4*)(a + k);
        const float aq[4] = {a4.x, a4.y, a4.z, a4.w};
#pragma unroll
        for (int q = 0; q < 4; ++q) {
            float4 b0 = *(const float4*)(B + (size_t)(k + q) * 8);
            float4 b1 = *(const float4*)(B + (size_t)(k + q) * 8 + 4);
            acc[0] += aq[q] * b0.x; acc[1] += aq[q] * b0.y;
            acc[2] += aq[q] * b0.z; acc[3] += aq[q] * b0.w;
            acc[4] += aq[q] * b1.x; acc[5] += aq[q] * b1.y;
            acc[6] += aq[q] * b1.z; acc[7] += aq[q] * b1.w;
        }
    }
#pragma unroll
    for (int off = 32; off > 0; off >>= 1) {
#pragma unroll
        for (int i = 0; i < 8; ++i) acc[i] += __shfl_down(acc[i], off);
    }
    if (lane == 0) {
#pragma unroll
        for (int i = 0; i < 8; ++i) C[(size_t)m * 8 + i] = acc[i];
    }
}

// Aggregation for fout=8 (final layer, +bias): one wave per node, lanes split edges.
// Padded edges (w=0, src=0) contribute nothing. xw8 is 320 KB -> L2-resident.
__global__ __launch_bounds__(64) void agg8_kernel(const float* __restrict__ xw,
                                                  const int* __restrict__ ptr,
                                                  const int* __restrict__ csr_src,
                                                  const float* __restrict__ csr_w,
                                                  const float* __restrict__ dinv,
                                                  const float* __restrict__ bias,
                                                  float* __restrict__ out) {
    int node = blockIdx.x;
    int lane = threadIdx.x;
    float acc[8] = {};
    int s = ptr[node], e = ptr[node + 1];
    for (int j = s + lane; j < e; j += 64) {
        int src = csr_src[j];
        float w = csr_w[j];
        float4 g0 = *(const float4*)(xw + (size_t)src * 8);
        float4 g1 = *(const float4*)(xw + (size_t)src * 8 + 4);
        acc[0] += w * g0.x; acc[1] += w * g0.y; acc[2] += w * g0.z; acc[3] += w * g0.w;
        acc[4] += w * g1.x; acc[5] += w * g1.y; acc[6] += w * g1.z; acc[7] += w * g1.w;
    }
#pragma unroll
    for (int off = 32; off > 0; off >>= 1) {
#pragma unroll
        for (int i = 0; i < 8; ++i) acc[i] += __shfl_down(acc[i], off);
    }
    if (lane == 0) {
        float di = dinv[node];
        float si = di * di;
#pragma unroll
        for (int i = 0; i < 8; ++i)
            out[(size_t)node * 8 + i] = acc[i] + si * xw[(size_t)node * 8 + i] + bias[i];
    }
}

// ---------------------------------------------------------------------------

extern "C" void kernel_launch(void* const* d_in, const int* in_sizes, int n_in,
                              void* d_out, int out_size, void* d_ws, size_t ws_size,
                              hipStream_t stream) {
    const int N = N_NODES, E = N_EDGES;
    const int N_PAD = ((N + TM - 1) / TM) * TM;   // 10112
    const float* x   = (const float*)d_in[0];
    const int*   ei  = (const int*)d_in[1];   // [2, E] (row=source, col=target)
    const float* ew  = (const float*)d_in[2];
    const float* W1  = (const float*)d_in[3];
    const float* b1  = (const float*)d_in[4];
    const float* W2  = (const float*)d_in[5];
    const float* b2  = (const float*)d_in[6];
    const float* W3  = (const float*)d_in[7];
    const float* b3  = (const float*)d_in[8];
    float* out = (float*)d_out;

    const int* row = ei;        // source
    const int* col = ei + E;    // target

    // workspace layout (256B-aligned); ~59 MB total
    char* ws = (char*)d_ws;
    size_t off = 0;
    auto alloc = [&](size_t bytes) {
        void* p = ws + off;
        off += (bytes + 255) & ~(size_t)255;
        return p;
    };
    float*          deg     = (float*)alloc((size_t)N * 4);
    float*          dinv    = (float*)alloc((size_t)N * 4);
    int*            counts  = (int*)alloc((size_t)N * 4);
    int*            cursor  = (int*)alloc((size_t)N * 4);
    int*            col_ptr = (int*)alloc((size_t)(N + 1) * 4);
    int*            csr_src = (int*)alloc((size_t)E_PAD * 4);
    float*          csr_w   = (float*)alloc((size_t)E_PAD * 4);
    float*          bufF    = (float*)alloc((size_t)N * 768 * 4);       // fp32 activations
    unsigned short* Ahi     = (unsigned short*)alloc((size_t)N_PAD * 512 * 2);
    unsigned short* Alo     = (unsigned short*)alloc((size_t)N_PAD * 512 * 2);
    unsigned short* W1thi   = (unsigned short*)alloc((size_t)512 * 256 * 2);
    unsigned short* W1tlo   = (unsigned short*)alloc((size_t)512 * 256 * 2);
    unsigned short* W2thi   = (unsigned short*)alloc((size_t)768 * 512 * 2);
    unsigned short* W2tlo   = (unsigned short*)alloc((size_t)768 * 512 * 2);
    float*          xw8     = (float*)alloc((size_t)N * 8 * 4);
    (void)ws_size;

    int nb_nodes = (N + 255) / 256;
    int nb_edges = (E + 255) / 256;

    // --- graph preprocessing (once; shared by all 3 layers) ---
    init_kernel<<<nb_nodes, 256, 0, stream>>>(deg, counts, cursor, N);
    zero_csr_kernel<<<(E_PAD + 255) / 256, 256, 0, stream>>>(csr_src, csr_w, E_PAD);
    deg_count_kernel<<<nb_edges, 256, 0, stream>>>(col, ew, deg, counts, E);
    scan_dinv_kernel<<<1, 1024, 0, stream>>>(counts, col_ptr, deg, dinv, N);
    scatter_kernel<<<nb_edges, 256, 0, stream>>>(row, col, ew, dinv, col_ptr, cursor,
                                                 csr_src, csr_w, E);

    // --- weight conversion (bf16 hi/lo, transposed), single launch ---
    {
        int tot = 256 * 512 + 512 * 768;
        convert_wt2_kernel<<<(tot + 255) / 256, 256, 0, stream>>>(
            W1, W1thi, W1tlo, 256, 512, W2, W2thi, W2tlo, 512, 768);
    }

    // --- layer 1: agg(256, 4 slices) -> mfma gemm 256->512 (+b1, relu) ---
    agg_slice_kernel<256, 2><<<N * 4, 64, 0, stream>>>(x, col_ptr, csr_src, csr_w,
                                                       dinv, Ahi, Alo);
    {
        dim3 grid(512 / TN, N_PAD / TM);
        gemm_mfma_kernel<<<grid, 256, 0, stream>>>(Ahi, Alo, W1thi, W1tlo, b1, bufF,
                                                   N, 256, 512, 1);
    }
    // --- layer 2: agg(512, 8 slices) -> mfma gemm 512->768 (+b2, relu) ---
    agg_slice_kernel<512, 3><<<N * 8, 64, 0, stream>>>(bufF, col_ptr, csr_src, csr_w,
                                                       dinv, Ahi, Alo);
    {
        dim3 grid(768 / TN, N_PAD / TM);
        gemm_mfma_kernel<<<grid, 256, 0, stream>>>(Ahi, Alo, W2thi, W2tlo, b2, bufF,
                                                   N, 512, 768, 1);
    }
    // --- layer 3: gemm 768->8 -> agg8 (+b3) ---
    gemm_n8_kernel<<<N, 64, 0, stream>>>(bufF, W3, xw8, 768);
    agg8_kernel<<<N, 64, 0, stream>>>(xw8, col_ptr, csr_src, csr_w, dinv, b3, out);

    (void)out_size; (void)n_in; (void)in_sizes;
}

// Round 9
// 285.563 us; speedup vs baseline: 1.2127x; 1.0537x over previous
//
#include <hip/hip_runtime.h>

#define N_NODES 10000
#define N_EDGES 320000
#define E_PAD (N_EDGES + 8 * N_NODES)   // CSR padded to 8-multiples per node

// ---------------------------------------------------------------------------
// bf16 helpers (RNE)
// ---------------------------------------------------------------------------
__device__ __forceinline__ unsigned short f2bf_rne(float v) {
    unsigned int u = __float_as_uint(v);
    return (unsigned short)((u + 0x7FFFu + ((u >> 16) & 1u)) >> 16);
}
__device__ __forceinline__ float bf2f(unsigned short h) {
    return __uint_as_float(((unsigned int)h) << 16);
}
// packed-pair unpack: u32 holds bf16 features (2j, 2j+1) little-endian
__device__ __forceinline__ float lo_f(unsigned int g) { return __uint_as_float(g << 16); }
__device__ __forceinline__ float hi_f(unsigned int g) { return __uint_as_float(g & 0xFFFF0000u); }

// ---------------------------------------------------------------------------
// Fused setup: deg/counts/cursor init + CSR zero + x->bf16 + W1/W2 hi/lo
// transpose.  All independent elementwise work, one launch.
// ---------------------------------------------------------------------------
__global__ __launch_bounds__(256) void setup_kernel(
        float* __restrict__ deg, int* __restrict__ counts, int* __restrict__ cursor,
        int* __restrict__ csr_src, float* __restrict__ csr_w,
        const float* __restrict__ x, unsigned short* __restrict__ xbf,
        const float* __restrict__ W1, unsigned short* __restrict__ w1h,
        unsigned short* __restrict__ w1l,
        const float* __restrict__ W2, unsigned short* __restrict__ w2h,
        unsigned short* __restrict__ w2l) {
    int i = blockIdx.x * 256 + threadIdx.x;
    const int S0 = N_NODES;                  // deg/counts/cursor
    const int S1 = S0 + E_PAD;               // csr zero
    const int S2 = S1 + N_NODES * 256;       // x -> bf16
    const int S3 = S2 + 256 * 512;           // W1
    const int S4 = S3 + 512 * 768;           // W2
    if (i < S0) {
        deg[i] = 1.0f; counts[i] = 0; cursor[i] = 0;
    } else if (i < S1) {
        int j = i - S0;
        csr_src[j] = 0; csr_w[j] = 0.f;
    } else if (i < S2) {
        int j = i - S1;
        xbf[j] = f2bf_rne(x[j]);
    } else if (i < S3) {
        int j = i - S2;
        int k = j >> 9, n = j & 511;         // W1 [256][512]
        float v = W1[j];
        unsigned short h = f2bf_rne(v);
        w1h[n * 256 + k] = h;
        w1l[n * 256 + k] = f2bf_rne(v - bf2f(h));
    } else if (i < S4) {
        int j = i - S3;
        int k = j / 768, n = j - k * 768;    // W2 [512][768]
        float v = W2[j];
        unsigned short h = f2bf_rne(v);
        w2h[n * 512 + k] = h;
        w2l[n * 512 + k] = f2bf_rne(v - bf2f(h));
    }
}

__global__ __launch_bounds__(256) void deg_count_kernel(const int* __restrict__ col,
                                                        const float* __restrict__ ew,
                                                        float* __restrict__ deg,
                                                        int* __restrict__ counts, int e) {
    int i = blockIdx.x * 256 + threadIdx.x;
    if (i < e) {
        int c = col[i];
        atomicAdd(deg + c, ew[i]);
        atomicAdd(counts + c, 1);
    }
}

// Single-block 1024-thread exclusive scan over 8-PADDED counts + fused dinv.
__global__ __launch_bounds__(1024) void scan_dinv_kernel(const int* __restrict__ counts,
                                                         int* __restrict__ ptr,
                                                         const float* __restrict__ deg,
                                                         float* __restrict__ dinv, int n) {
    __shared__ int wsum[16];
    __shared__ int woff[16];
    __shared__ int carry_s, tot_s;
    const int lane = threadIdx.x & 63;
    const int wid = threadIdx.x >> 6;
    if (threadIdx.x == 0) carry_s = 0;
    __syncthreads();
    for (int base = 0; base < n; base += 1024) {
        int i = base + (int)threadIdx.x;
        int v = (i < n) ? ((counts[i] + 7) & ~7) : 0;   // pad to multiple of 8
        if (i < n) {
            float d = deg[i];
            dinv[i] = (d > 0.0f) ? rsqrtf(d) : 0.0f;
        }
        int x = v;
#pragma unroll
        for (int off = 1; off < 64; off <<= 1) {
            int t = __shfl_up(x, off);
            if (lane >= off) x += t;
        }
        if (lane == 63) wsum[wid] = x;
        __syncthreads();
        if (wid == 0) {
            int s = (lane < 16) ? wsum[lane] : 0;
            int y = s;
#pragma unroll
            for (int off = 1; off < 16; off <<= 1) {
                int t = __shfl_up(y, off);
                if (lane >= off) y += t;
            }
            if (lane < 16) woff[lane] = y - s;
            if (lane == 15) tot_s = y;
        }
        __syncthreads();
        int carry = carry_s;
        if (i < n) ptr[i] = carry + woff[wid] + x - v;
        __syncthreads();
        if (threadIdx.x == 0) carry_s = carry + tot_s;
        __syncthreads();
    }
    if (threadIdx.x == 0) ptr[n] = carry_s;
}

__global__ __launch_bounds__(256) void scatter_kernel(const int* __restrict__ row,
                                                      const int* __restrict__ col,
                                                      const float* __restrict__ ew,
                                                      const float* __restrict__ dinv,
                                                      const int* __restrict__ ptr,
                                                      int* __restrict__ cursor,
                                                      int* __restrict__ csr_src,
                                                      float* __restrict__ csr_w, int e) {
    int i = blockIdx.x * 256 + threadIdx.x;
    if (i < e) {
        int c = col[i], r = row[i];
        int pos = ptr[c] + atomicAdd(cursor + c, 1);
        csr_src[pos] = r;
        csr_w[pos] = dinv[r] * ew[i] * dinv[c];
    }
}

// ---------------------------------------------------------------------------
// XCD-sliced aggregation over PACKED bf16 activations, split-bf16 output:
//   acc[n,f] = dinv[n]^2 * x[n,f] + sum_in w * x[src,f]   (fp32 accumulate)
// One wave per (node, 64-PAIR slice = 128 features); lane = one u32 pair.
// node = blockIdx>>shift is UNIFORM -> metadata scalarized (s_load), gather
// base in SGPR, ZERO VALU addr math per gather.  [R7/R8 lesson]
// Slab per slice = 10000 x 128 x 2B = 2.56 MB < 4 MB per-XCD L2.
// Gather = 1 dword/lane = 2 features -> half the issues & bytes of fp32.
// ---------------------------------------------------------------------------
template <int F, int SSHIFT>
__global__ __launch_bounds__(64) void agg_slice_kernel(const unsigned int* __restrict__ xpk,
                                                       const int* __restrict__ ptr,
                                                       const int* __restrict__ csr_src,
                                                       const float* __restrict__ csr_w,
                                                       const float* __restrict__ dinv,
                                                       unsigned int* __restrict__ ohi,
                                                       unsigned int* __restrict__ olo) {
    constexpr int F2 = F / 2;
    const int b = blockIdx.x;
    const int slice = b & ((1 << SSHIFT) - 1);
    const int node = b >> SSHIFT;                 // uniform
    const int f2 = slice * 64 + (int)threadIdx.x; // pair index
    const float di = dinv[node];
    const float si = di * di;
    unsigned int gs = xpk[node * F2 + f2];
    float acc0 = si * lo_f(gs);
    float acc1 = si * hi_f(gs);
    const int s = ptr[node], e = ptr[node + 1];   // 8-aligned, length % 8 == 0

    for (int j = s; j < e; j += 8) {
        // uniform indices -> scalar loads; weights land in SGPRs
        int s0 = csr_src[j + 0], s1 = csr_src[j + 1], s2 = csr_src[j + 2], s3 = csr_src[j + 3];
        int s4 = csr_src[j + 4], s5 = csr_src[j + 5], s6 = csr_src[j + 6], s7 = csr_src[j + 7];
        float w0 = csr_w[j + 0], w1 = csr_w[j + 1], w2 = csr_w[j + 2], w3 = csr_w[j + 3];
        float w4 = csr_w[j + 4], w5 = csr_w[j + 5], w6 = csr_w[j + 6], w7 = csr_w[j + 7];
        // 8 independent dword gathers in flight (scalar bases)
        unsigned int g0 = xpk[s0 * F2 + f2];
        unsigned int g1 = xpk[s1 * F2 + f2];
        unsigned int g2 = xpk[s2 * F2 + f2];
        unsigned int g3 = xpk[s3 * F2 + f2];
        unsigned int g4 = xpk[s4 * F2 + f2];
        unsigned int g5 = xpk[s5 * F2 + f2];
        unsigned int g6 = xpk[s6 * F2 + f2];
        unsigned int g7 = xpk[s7 * F2 + f2];
        acc0 += w0 * lo_f(g0) + w1 * lo_f(g1) + w2 * lo_f(g2) + w3 * lo_f(g3);
        acc1 += w0 * hi_f(g0) + w1 * hi_f(g1) + w2 * hi_f(g2) + w3 * hi_f(g3);
        acc0 += w4 * lo_f(g4) + w5 * lo_f(g5) + w6 * lo_f(g6) + w7 * lo_f(g7);
        acc1 += w4 * hi_f(g4) + w5 * hi_f(g5) + w6 * hi_f(g6) + w7 * hi_f(g7);
    }

    unsigned short h0 = f2bf_rne(acc0);
    unsigned short l0 = f2bf_rne(acc0 - bf2f(h0));
    unsigned short h1 = f2bf_rne(acc1);
    unsigned short l1 = f2bf_rne(acc1 - bf2f(h1));
    ohi[node * F2 + f2] = ((unsigned int)h1 << 16) | h0;
    olo[node * F2 + f2] = ((unsigned int)l1 << 16) | l0;
}

// ---------------------------------------------------------------------------
// Split-bf16 MFMA GEMM + bias (+relu), async global->LDS staging.
//   C[M,N] = (Ahi+Alo)[M,K] @ (Bhi+Blo)[K,N] + bias   (lo*lo dropped)
// B transposed as Bt[N][K]; A row-padded to TM multiple (pad rows discarded).
// Tile 128m x 128n, BK=32, 256 threads = 4 waves of 64m x 64n.
// Output: fp32 (Cf) or bf16 (Cb) per out_bf16 flag (bf16 feeds next agg).
// ---------------------------------------------------------------------------
typedef short bf16x8 __attribute__((ext_vector_type(8)));
typedef float f32x4 __attribute__((ext_vector_type(4)));

#define TM 128
#define TN 128
#define BK 32
#define LDS_A_HI 0
#define LDS_A_LO 8192
#define LDS_B_HI 16384
#define LDS_B_LO 24576
#define LDS_BUF  32768

__device__ __forceinline__ void async16(const unsigned short* g, unsigned char* l) {
    __builtin_amdgcn_global_load_lds(
        (const __attribute__((address_space(1))) unsigned int*)g,
        (__attribute__((address_space(3))) unsigned int*)l, 16, 0, 0);
}

__global__ __launch_bounds__(256, 2) void gemm_mfma_kernel(
        const unsigned short* __restrict__ Ahi,
        const unsigned short* __restrict__ Alo,
        const unsigned short* __restrict__ Bthi,
        const unsigned short* __restrict__ Btlo,
        const float* __restrict__ bias,
        float* __restrict__ Cf,
        unsigned short* __restrict__ Cb,
        int M, int K, int N, int relu, int out_bf16) {
    __shared__ unsigned char lds[2 * LDS_BUF];
    const int t = (int)threadIdx.x;
    const int bm = blockIdx.y * TM;
    const int bn = blockIdx.x * TN;
    const int lane = t & 63;
    const int wave = t >> 6;
    const int wm = (wave & 1) * 64;
    const int wn = (wave >> 1) * 64;

    // ---- staging geometry (per lane): 16-row blocks, 1024 B per async issue ----
    const int slr = lane >> 2;                       // 0..15 local row
    const int scc = (lane & 3) ^ ((slr >> 1) & 3);   // swizzled global chunk
    const int bi0 = wave * 2, bi1 = wave * 2 + 1;    // 16-row block ids (0..7)
    const unsigned short* gA0h = Ahi + (size_t)(bm + bi0 * 16 + slr) * K + scc * 8;
    const unsigned short* gA1h = Ahi + (size_t)(bm + bi1 * 16 + slr) * K + scc * 8;
    const unsigned short* gA0l = Alo + (size_t)(bm + bi0 * 16 + slr) * K + scc * 8;
    const unsigned short* gA1l = Alo + (size_t)(bm + bi1 * 16 + slr) * K + scc * 8;
    const unsigned short* gB0h = Bthi + (size_t)(bn + bi0 * 16 + slr) * K + scc * 8;
    const unsigned short* gB1h = Bthi + (size_t)(bn + bi1 * 16 + slr) * K + scc * 8;
    const unsigned short* gB0l = Btlo + (size_t)(bn + bi0 * 16 + slr) * K + scc * 8;
    const unsigned short* gB1l = Btlo + (size_t)(bn + bi1 * 16 + slr) * K + scc * 8;

    // ---- fragment read geometry ----
    const int quad = lane >> 4;
    const int lr16 = lane & 15;
    const int fs = (quad ^ ((lr16 >> 1) & 3)) * 16;  // swizzled slot byte offset

    f32x4 acc[4][4];
    const f32x4 zero4 = {0.f, 0.f, 0.f, 0.f};
#pragma unroll
    for (int i = 0; i < 4; ++i)
#pragma unroll
        for (int j = 0; j < 4; ++j) acc[i][j] = zero4;

    const int KT = K / BK;

    auto stage = [&](int kt, int buf) {
        const int k0 = kt * BK;
        unsigned char* b = &lds[buf * LDS_BUF];
        async16(gA0h + k0, b + LDS_A_HI + bi0 * 1024);
        async16(gA1h + k0, b + LDS_A_HI + bi1 * 1024);
        async16(gA0l + k0, b + LDS_A_LO + bi0 * 1024);
        async16(gA1l + k0, b + LDS_A_LO + bi1 * 1024);
        async16(gB0h + k0, b + LDS_B_HI + bi0 * 1024);
        async16(gB1h + k0, b + LDS_B_HI + bi1 * 1024);
        async16(gB0l + k0, b + LDS_B_LO + bi0 * 1024);
        async16(gB1l + k0, b + LDS_B_LO + bi1 * 1024);
    };

    stage(0, 0);
    __syncthreads();

    for (int kt = 0; kt < KT; ++kt) {
        const int buf = kt & 1;
        if (kt + 1 < KT) stage(kt + 1, buf ^ 1);   // async, drains at barrier below

        unsigned char* b = &lds[buf * LDS_BUF];
        bf16x8 ah[4], al[4], bh[4], bl[4];
#pragma unroll
        for (int i = 0; i < 4; ++i) {
            int ro = (wm + i * 16 + lr16) * 64 + fs;
            ah[i] = *(const bf16x8*)(b + LDS_A_HI + ro);
            al[i] = *(const bf16x8*)(b + LDS_A_LO + ro);
        }
#pragma unroll
        for (int j = 0; j < 4; ++j) {
            int ro = (wn + j * 16 + lr16) * 64 + fs;
            bh[j] = *(const bf16x8*)(b + LDS_B_HI + ro);
            bl[j] = *(const bf16x8*)(b + LDS_B_LO + ro);
        }
#pragma unroll
        for (int i = 0; i < 4; ++i)
#pragma unroll
            for (int j = 0; j < 4; ++j) {
                acc[i][j] = __builtin_amdgcn_mfma_f32_16x16x32_bf16(ah[i], bh[j], acc[i][j], 0, 0, 0);
                acc[i][j] = __builtin_amdgcn_mfma_f32_16x16x32_bf16(ah[i], bl[j], acc[i][j], 0, 0, 0);
                acc[i][j] = __builtin_amdgcn_mfma_f32_16x16x32_bf16(al[i], bh[j], acc[i][j], 0, 0, 0);
            }
        __syncthreads();
    }

    // epilogue: bias (+relu), store fp32 or bf16
    float bcol[4];
#pragma unroll
    for (int j = 0; j < 4; ++j) bcol[j] = bias[bn + wn + j * 16 + lr16];
#pragma unroll
    for (int i = 0; i < 4; ++i) {
#pragma unroll
        for (int r = 0; r < 4; ++r) {
            int m = bm + wm + i * 16 + quad * 4 + r;
            if (m < M) {
#pragma unroll
                for (int j = 0; j < 4; ++j) {
                    float vv = acc[i][j][r] + bcol[j];
                    if (relu) vv = fmaxf(vv, 0.f);
                    int col = bn + wn + j * 16 + lr16;
                    if (out_bf16) Cb[(size_t)m * N + col] = f2bf_rne(vv);
                    else          Cf[(size_t)m * N + col] = vv;
                }
            }
        }
    }
}

// ---------------------------------------------------------------------------
// GEMM for layer 3: N=8, K=768.  One wave per row; float4 A loads.
// ---------------------------------------------------------------------------
__global__ __launch_bounds__(64) void gemm_n8_kernel(const float* __restrict__ A,
                                                     const float* __restrict__ B,
                                                     float* __restrict__ C, int K) {
    int m = blockIdx.x;
    int lane = threadIdx.x;
    const float* a = A + (size_t)m * K;
    float acc[8] = {};
    for (int k = lane * 4; k < K; k += 256) {
        float4 a4 = *(const float4*)(a + k);
        const float aq[4] = {a4.x, a4.y, a4.z, a4.w};
#pragma unroll
        for (int q = 0; q < 4; ++q) {
            float4 b0 = *(const float4*)(B + (size_t)(k + q) * 8);
            float4 b1 = *(const float4*)(B + (size_t)(k + q) * 8 + 4);
            acc[0] += aq[q] * b0.x; acc[1] += aq[q] * b0.y;
            acc[2] += aq[q] * b0.z; acc[3] += aq[q] * b0.w;
            acc[4] += aq[q] * b1.x; acc[5] += aq[q] * b1.y;
            acc[6] += aq[q] * b1.z; acc[7] += aq[q] * b1.w;
        }
    }
#pragma unroll
    for (int off = 32; off > 0; off >>= 1) {
#pragma unroll
        for (int i = 0; i < 8; ++i) acc[i] += __shfl_down(acc[i], off);
    }
    if (lane == 0) {
#pragma unroll
        for (int i = 0; i < 8; ++i) C[(size_t)m * 8 + i] = acc[i];
    }
}

// Aggregation for fout=8 (final layer, +bias): one wave per node, lanes split edges.
__global__ __launch_bounds__(64) void agg8_kernel(const float* __restrict__ xw,
                                                  const int* __restrict__ ptr,
                                                  const int* __restrict__ csr_src,
                                                  const float* __restrict__ csr_w,
                                                  const float* __restrict__ dinv,
                                                  const float* __restrict__ bias,
                                                  float* __restrict__ out) {
    int node = blockIdx.x;
    int lane = threadIdx.x;
    float acc[8] = {};
    int s = ptr[node], e = ptr[node + 1];
    for (int j = s + lane; j < e; j += 64) {
        int src = csr_src[j];
        float w = csr_w[j];
        float4 g0 = *(const float4*)(xw + (size_t)src * 8);
        float4 g1 = *(const float4*)(xw + (size_t)src * 8 + 4);
        acc[0] += w * g0.x; acc[1] += w * g0.y; acc[2] += w * g0.z; acc[3] += w * g0.w;
        acc[4] += w * g1.x; acc[5] += w * g1.y; acc[6] += w * g1.z; acc[7] += w * g1.w;
    }
#pragma unroll
    for (int off = 32; off > 0; off >>= 1) {
#pragma unroll
        for (int i = 0; i < 8; ++i) acc[i] += __shfl_down(acc[i], off);
    }
    if (lane == 0) {
        float di = dinv[node];
        float si = di * di;
#pragma unroll
        for (int i = 0; i < 8; ++i)
            out[(size_t)node * 8 + i] = acc[i] + si * xw[(size_t)node * 8 + i] + bias[i];
    }
}

// ---------------------------------------------------------------------------

extern "C" void kernel_launch(void* const* d_in, const int* in_sizes, int n_in,
                              void* d_out, int out_size, void* d_ws, size_t ws_size,
                              hipStream_t stream) {
    const int N = N_NODES, E = N_EDGES;
    const int N_PAD = ((N + TM - 1) / TM) * TM;   // 10112
    const float* x   = (const float*)d_in[0];
    const int*   ei  = (const int*)d_in[1];   // [2, E] (row=source, col=target)
    const float* ew  = (const float*)d_in[2];
    const float* W1  = (const float*)d_in[3];
    const float* b1  = (const float*)d_in[4];
    const float* W2  = (const float*)d_in[5];
    const float* b2  = (const float*)d_in[6];
    const float* W3  = (const float*)d_in[7];
    const float* b3  = (const float*)d_in[8];
    float* out = (float*)d_out;

    const int* row = ei;        // source
    const int* col = ei + E;    // target

    // workspace layout (256B-aligned); ~60 MB total
    char* ws = (char*)d_ws;
    size_t off = 0;
    auto alloc = [&](size_t bytes) {
        void* p = ws + off;
        off += (bytes + 255) & ~(size_t)255;
        return p;
    };
    float*          deg     = (float*)alloc((size_t)N * 4);
    float*          dinv    = (float*)alloc((size_t)N * 4);
    int*            counts  = (int*)alloc((size_t)N * 4);
    int*            cursor  = (int*)alloc((size_t)N * 4);
    int*            col_ptr = (int*)alloc((size_t)(N + 1) * 4);
    int*            csr_src = (int*)alloc((size_t)E_PAD * 4);
    float*          csr_w   = (float*)alloc((size_t)E_PAD * 4);
    float*          bufF    = (float*)alloc((size_t)N * 768 * 4);        // gemm2 out fp32
    unsigned short* xbf     = (unsigned short*)alloc((size_t)N * 256 * 2);   // x as bf16
    unsigned short* h1bf    = (unsigned short*)alloc((size_t)N * 512 * 2);   // gemm1 out bf16
    unsigned short* Ahi     = (unsigned short*)alloc((size_t)N_PAD * 512 * 2);
    unsigned short* Alo     = (unsigned short*)alloc((size_t)N_PAD * 512 * 2);
    unsigned short* W1thi   = (unsigned short*)alloc((size_t)512 * 256 * 2);
    unsigned short* W1tlo   = (unsigned short*)alloc((size_t)512 * 256 * 2);
    unsigned short* W2thi   = (unsigned short*)alloc((size_t)768 * 512 * 2);
    unsigned short* W2tlo   = (unsigned short*)alloc((size_t)768 * 512 * 2);
    float*          xw8     = (float*)alloc((size_t)N * 8 * 4);
    (void)ws_size;

    int nb_edges = (E + 255) / 256;

    // --- fused setup (init + CSR zero + x->bf16 + weight conversion) ---
    {
        int tot = N + E_PAD + N * 256 + 256 * 512 + 512 * 768;
        setup_kernel<<<(tot + 255) / 256, 256, 0, stream>>>(
            deg, counts, cursor, csr_src, csr_w, x, xbf,
            W1, W1thi, W1tlo, W2, W2thi, W2tlo);
    }
    deg_count_kernel<<<nb_edges, 256, 0, stream>>>(col, ew, deg, counts, E);
    scan_dinv_kernel<<<1, 1024, 0, stream>>>(counts, col_ptr, deg, dinv, N);
    scatter_kernel<<<nb_edges, 256, 0, stream>>>(row, col, ew, dinv, col_ptr, cursor,
                                                 csr_src, csr_w, E);

    // --- layer 1: agg(bf16 x, 2 slices of 128 feats) -> gemm 256->512 (+b1, relu, bf16 out)
    agg_slice_kernel<256, 1><<<N * 2, 64, 0, stream>>>(
        (const unsigned int*)xbf, col_ptr, csr_src, csr_w, dinv,
        (unsigned int*)Ahi, (unsigned int*)Alo);
    {
        dim3 grid(512 / TN, N_PAD / TM);
        gemm_mfma_kernel<<<grid, 256, 0, stream>>>(Ahi, Alo, W1thi, W1tlo, b1,
                                                   nullptr, h1bf, N, 256, 512, 1, 1);
    }
    // --- layer 2: agg(bf16 h1, 4 slices of 128 feats) -> gemm 512->768 (+b2, relu, fp32 out)
    agg_slice_kernel<512, 2><<<N * 4, 64, 0, stream>>>(
        (const unsigned int*)h1bf, col_ptr, csr_src, csr_w, dinv,
        (unsigned int*)Ahi, (unsigned int*)Alo);
    {
        dim3 grid(768 / TN, N_PAD / TM);
        gemm_mfma_kernel<<<grid, 256, 0, stream>>>(Ahi, Alo, W2thi, W2tlo, b2,
                                                   bufF, nullptr, N, 512, 768, 1, 0);
    }
    // --- layer 3: gemm 768->8 -> agg8 (+b3) ---
    gemm_n8_kernel<<<N, 64, 0, stream>>>(bufF, W3, xw8, 768);
    agg8_kernel<<<N, 64, 0, stream>>>(xw8, col_ptr, csr_src, csr_w, dinv, b3, out);

    (void)out_size; (void)n_in; (void)in_sizes;
}

// Round 10
// 256.041 us; speedup vs baseline: 1.3526x; 1.1153x over previous
//
#include <hip/hip_runtime.h>

#define N_NODES 10000
#define N_EDGES 320000
#define E_PAD (N_EDGES + 8 * N_NODES)   // CSR padded to 8-multiples per node

// ---------------------------------------------------------------------------
// bf16 helpers (RNE)
// ---------------------------------------------------------------------------
__device__ __forceinline__ unsigned short f2bf_rne(float v) {
    unsigned int u = __float_as_uint(v);
    return (unsigned short)((u + 0x7FFFu + ((u >> 16) & 1u)) >> 16);
}
__device__ __forceinline__ float bf2f(unsigned short h) {
    return __uint_as_float(((unsigned int)h) << 16);
}
// packed-pair unpack: u32 holds bf16 features (2j, 2j+1) little-endian
__device__ __forceinline__ float lo_f(unsigned int g) { return __uint_as_float(g << 16); }
__device__ __forceinline__ float hi_f(unsigned int g) { return __uint_as_float(g & 0xFFFF0000u); }

// ---------------------------------------------------------------------------
// Fused setup: deg/counts init + CSR zero + x->bf16 + W1/W2 hi/lo transpose.
// ---------------------------------------------------------------------------
__global__ __launch_bounds__(256) void setup_kernel(
        float* __restrict__ deg, int* __restrict__ counts,
        int* __restrict__ csr_src, float* __restrict__ csr_w,
        const float* __restrict__ x, unsigned short* __restrict__ xbf,
        const float* __restrict__ W1, unsigned short* __restrict__ w1h,
        unsigned short* __restrict__ w1l,
        const float* __restrict__ W2, unsigned short* __restrict__ w2h,
        unsigned short* __restrict__ w2l) {
    int i = blockIdx.x * 256 + threadIdx.x;
    const int S0 = N_NODES;                  // deg/counts
    const int S1 = S0 + E_PAD;               // csr zero
    const int S2 = S1 + N_NODES * 256;       // x -> bf16
    const int S3 = S2 + 256 * 512;           // W1
    const int S4 = S3 + 512 * 768;           // W2
    if (i < S0) {
        deg[i] = 1.0f; counts[i] = 0;        // self-loop weight 1
    } else if (i < S1) {
        int j = i - S0;
        csr_src[j] = 0; csr_w[j] = 0.f;      // pad edges: node 0, weight 0
    } else if (i < S2) {
        int j = i - S1;
        xbf[j] = f2bf_rne(x[j]);
    } else if (i < S3) {
        int j = i - S2;
        int k = j >> 9, n = j & 511;         // W1 [256][512]
        float v = W1[j];
        unsigned short h = f2bf_rne(v);
        w1h[n * 256 + k] = h;
        w1l[n * 256 + k] = f2bf_rne(v - bf2f(h));
    } else if (i < S4) {
        int j = i - S3;
        int k = j / 768, n = j - k * 768;    // W2 [512][768]
        float v = W2[j];
        unsigned short h = f2bf_rne(v);
        w2h[n * 512 + k] = h;
        w2l[n * 512 + k] = f2bf_rne(v - bf2f(h));
    }
}

// Degree + count with slot recording: slot[i] = this edge's rank within its
// destination segment -> scatter needs no atomics.
__global__ __launch_bounds__(256) void count_slot_kernel(const int* __restrict__ col,
                                                         const float* __restrict__ ew,
                                                         float* __restrict__ deg,
                                                         int* __restrict__ counts,
                                                         int* __restrict__ slot, int e) {
    int i = blockIdx.x * 256 + threadIdx.x;
    if (i < e) {
        int c = col[i];
        slot[i] = atomicAdd(counts + c, 1);
        atomicAdd(deg + c, ew[i]);
    }
}

// Single-block scan, 2 barriers: each thread owns 10 contiguous counts
// (local serial prefix), then wave-scan + 16-partial block scan.
// Emits 8-padded exclusive ptr + fused dinv.
__global__ __launch_bounds__(1024) void scan_dinv_kernel(const int* __restrict__ counts,
                                                         int* __restrict__ ptr,
                                                         const float* __restrict__ deg,
                                                         float* __restrict__ dinv, int n) {
    __shared__ int wsum[16];
    __shared__ int woff[16];
    const int t = (int)threadIdx.x;
    const int lane = t & 63;
    const int wid = t >> 6;
    const int base = t * 10;
    int loc[10];
    int tot = 0;
#pragma unroll
    for (int q = 0; q < 10; ++q) {
        int i = base + q;
        int v = 0;
        if (i < n) {
            v = (counts[i] + 7) & ~7;        // pad to multiple of 8
            float d = deg[i];
            dinv[i] = (d > 0.0f) ? rsqrtf(d) : 0.0f;
        }
        loc[q] = tot;                        // exclusive local prefix
        tot += v;
    }
    int x = tot;                             // wave-inclusive scan of totals
#pragma unroll
    for (int off = 1; off < 64; off <<= 1) {
        int u = __shfl_up(x, off);
        if (lane >= off) x += u;
    }
    if (lane == 63) wsum[wid] = x;
    __syncthreads();                         // B1
    if (wid == 0 && lane < 16) {
        int s = wsum[lane];
        int y = s;
#pragma unroll
        for (int off = 1; off < 16; off <<= 1) {
            int u = __shfl_up(y, off);
            if (lane >= off) y += u;
        }
        woff[lane] = y - s;                  // exclusive wave offsets
        if (lane == 15) ptr[n] = y;          // grand total
    }
    __syncthreads();                         // B2
    const int tbase = woff[wid] + (x - tot); // thread's exclusive offset
#pragma unroll
    for (int q = 0; q < 10; ++q) {
        int i = base + q;
        if (i < n) ptr[i] = tbase + loc[q];
    }
}

// Scatter without atomics: pos = ptr[col] + precomputed slot.
__global__ __launch_bounds__(256) void scatter_kernel(const int* __restrict__ row,
                                                      const int* __restrict__ col,
                                                      const float* __restrict__ ew,
                                                      const float* __restrict__ dinv,
                                                      const int* __restrict__ ptr,
                                                      const int* __restrict__ slot,
                                                      int* __restrict__ csr_src,
                                                      float* __restrict__ csr_w, int e) {
    int i = blockIdx.x * 256 + threadIdx.x;
    if (i < e) {
        int c = col[i], r = row[i];
        int pos = ptr[c] + slot[i];
        csr_src[pos] = r;
        csr_w[pos] = dinv[r] * ew[i] * dinv[c];
    }
}

// ---------------------------------------------------------------------------
// XCD-sliced aggregation over PACKED bf16 activations, split-bf16 output:
//   acc[n,f] = dinv[n]^2 * x[n,f] + sum_in w * x[src,f]   (fp32 accumulate)
// One wave per (node, 64-PAIR slice = 128 features); lane = one u32 pair.
// node = blockIdx>>shift is UNIFORM -> metadata scalarized (s_load), gather
// base in SGPR.  [R7/R8 lesson: never derive node from threadIdx]
// Slab per slice = 10000 x 128 x 2B = 2.56 MB < 4 MB per-XCD L2.
// ---------------------------------------------------------------------------
template <int F, int SSHIFT>
__global__ __launch_bounds__(64) void agg_slice_kernel(const unsigned int* __restrict__ xpk,
                                                       const int* __restrict__ ptr,
                                                       const int* __restrict__ csr_src,
                                                       const float* __restrict__ csr_w,
                                                       const float* __restrict__ dinv,
                                                       unsigned int* __restrict__ ohi,
                                                       unsigned int* __restrict__ olo) {
    constexpr int F2 = F / 2;
    const int b = blockIdx.x;
    const int slice = b & ((1 << SSHIFT) - 1);
    const int node = b >> SSHIFT;                 // uniform
    const int f2 = slice * 64 + (int)threadIdx.x; // pair index
    const float di = dinv[node];
    const float si = di * di;
    unsigned int gs = xpk[node * F2 + f2];
    float acc0 = si * lo_f(gs);
    float acc1 = si * hi_f(gs);
    const int s = ptr[node], e = ptr[node + 1];   // 8-aligned, length % 8 == 0

    for (int j = s; j < e; j += 8) {
        // uniform indices -> scalar loads; weights land in SGPRs
        int s0 = csr_src[j + 0], s1 = csr_src[j + 1], s2 = csr_src[j + 2], s3 = csr_src[j + 3];
        int s4 = csr_src[j + 4], s5 = csr_src[j + 5], s6 = csr_src[j + 6], s7 = csr_src[j + 7];
        float w0 = csr_w[j + 0], w1 = csr_w[j + 1], w2 = csr_w[j + 2], w3 = csr_w[j + 3];
        float w4 = csr_w[j + 4], w5 = csr_w[j + 5], w6 = csr_w[j + 6], w7 = csr_w[j + 7];
        // 8 independent dword gathers in flight (scalar bases)
        unsigned int g0 = xpk[s0 * F2 + f2];
        unsigned int g1 = xpk[s1 * F2 + f2];
        unsigned int g2 = xpk[s2 * F2 + f2];
        unsigned int g3 = xpk[s3 * F2 + f2];
        unsigned int g4 = xpk[s4 * F2 + f2];
        unsigned int g5 = xpk[s5 * F2 + f2];
        unsigned int g6 = xpk[s6 * F2 + f2];
        unsigned int g7 = xpk[s7 * F2 + f2];
        acc0 += w0 * lo_f(g0) + w1 * lo_f(g1) + w2 * lo_f(g2) + w3 * lo_f(g3);
        acc1 += w0 * hi_f(g0) + w1 * hi_f(g1) + w2 * hi_f(g2) + w3 * hi_f(g3);
        acc0 += w4 * lo_f(g4) + w5 * lo_f(g5) + w6 * lo_f(g6) + w7 * lo_f(g7);
        acc1 += w4 * hi_f(g4) + w5 * hi_f(g5) + w6 * hi_f(g6) + w7 * hi_f(g7);
    }

    unsigned short h0 = f2bf_rne(acc0);
    unsigned short l0 = f2bf_rne(acc0 - bf2f(h0));
    unsigned short h1 = f2bf_rne(acc1);
    unsigned short l1 = f2bf_rne(acc1 - bf2f(h1));
    ohi[node * F2 + f2] = ((unsigned int)h1 << 16) | h0;
    olo[node * F2 + f2] = ((unsigned int)l1 << 16) | l0;
}

// ---------------------------------------------------------------------------
// Split-bf16 MFMA GEMM + bias + relu, async global->LDS staging, bf16 output.
//   C[M,N] = (Ahi+Alo)[M,K] @ (Bhi+Blo)[K,N] + bias   (lo*lo dropped)
// B transposed as Bt[N][K]; A row-padded to TM multiple (pad rows discarded).
// Tile 128m x 128n, BK=32, 256 threads = 4 waves of 64m x 64n.
// ---------------------------------------------------------------------------
typedef short bf16x8 __attribute__((ext_vector_type(8)));
typedef float f32x4 __attribute__((ext_vector_type(4)));

#define TM 128
#define TN 128
#define BK 32
#define LDS_A_HI 0
#define LDS_A_LO 8192
#define LDS_B_HI 16384
#define LDS_B_LO 24576
#define LDS_BUF  32768

__device__ __forceinline__ void async16(const unsigned short* g, unsigned char* l) {
    __builtin_amdgcn_global_load_lds(
        (const __attribute__((address_space(1))) unsigned int*)g,
        (__attribute__((address_space(3))) unsigned int*)l, 16, 0, 0);
}

__global__ __launch_bounds__(256, 2) void gemm_mfma_kernel(
        const unsigned short* __restrict__ Ahi,
        const unsigned short* __restrict__ Alo,
        const unsigned short* __restrict__ Bthi,
        const unsigned short* __restrict__ Btlo,
        const float* __restrict__ bias,
        unsigned short* __restrict__ Cb,
        int M, int K, int N) {
    __shared__ unsigned char lds[2 * LDS_BUF];
    const int t = (int)threadIdx.x;
    const int bm = blockIdx.y * TM;
    const int bn = blockIdx.x * TN;
    const int lane = t & 63;
    const int wave = t >> 6;
    const int wm = (wave & 1) * 64;
    const int wn = (wave >> 1) * 64;

    // ---- staging geometry (per lane): 16-row blocks, 1024 B per async issue ----
    const int slr = lane >> 2;                       // 0..15 local row
    const int scc = (lane & 3) ^ ((slr >> 1) & 3);   // swizzled global chunk
    const int bi0 = wave * 2, bi1 = wave * 2 + 1;    // 16-row block ids (0..7)
    const unsigned short* gA0h = Ahi + (size_t)(bm + bi0 * 16 + slr) * K + scc * 8;
    const unsigned short* gA1h = Ahi + (size_t)(bm + bi1 * 16 + slr) * K + scc * 8;
    const unsigned short* gA0l = Alo + (size_t)(bm + bi0 * 16 + slr) * K + scc * 8;
    const unsigned short* gA1l = Alo + (size_t)(bm + bi1 * 16 + slr) * K + scc * 8;
    const unsigned short* gB0h = Bthi + (size_t)(bn + bi0 * 16 + slr) * K + scc * 8;
    const unsigned short* gB1h = Bthi + (size_t)(bn + bi1 * 16 + slr) * K + scc * 8;
    const unsigned short* gB0l = Btlo + (size_t)(bn + bi0 * 16 + slr) * K + scc * 8;
    const unsigned short* gB1l = Btlo + (size_t)(bn + bi1 * 16 + slr) * K + scc * 8;

    // ---- fragment read geometry ----
    const int quad = lane >> 4;
    const int lr16 = lane & 15;
    const int fs = (quad ^ ((lr16 >> 1) & 3)) * 16;  // swizzled slot byte offset

    f32x4 acc[4][4];
    const f32x4 zero4 = {0.f, 0.f, 0.f, 0.f};
#pragma unroll
    for (int i = 0; i < 4; ++i)
#pragma unroll
        for (int j = 0; j < 4; ++j) acc[i][j] = zero4;

    const int KT = K / BK;

    auto stage = [&](int kt, int buf) {
        const int k0 = kt * BK;
        unsigned char* b = &lds[buf * LDS_BUF];
        async16(gA0h + k0, b + LDS_A_HI + bi0 * 1024);
        async16(gA1h + k0, b + LDS_A_HI + bi1 * 1024);
        async16(gA0l + k0, b + LDS_A_LO + bi0 * 1024);
        async16(gA1l + k0, b + LDS_A_LO + bi1 * 1024);
        async16(gB0h + k0, b + LDS_B_HI + bi0 * 1024);
        async16(gB1h + k0, b + LDS_B_HI + bi1 * 1024);
        async16(gB0l + k0, b + LDS_B_LO + bi0 * 1024);
        async16(gB1l + k0, b + LDS_B_LO + bi1 * 1024);
    };

    stage(0, 0);
    __syncthreads();

    for (int kt = 0; kt < KT; ++kt) {
        const int buf = kt & 1;
        if (kt + 1 < KT) stage(kt + 1, buf ^ 1);   // async, drains at barrier below

        unsigned char* b = &lds[buf * LDS_BUF];
        bf16x8 ah[4], al[4], bh[4], bl[4];
#pragma unroll
        for (int i = 0; i < 4; ++i) {
            int ro = (wm + i * 16 + lr16) * 64 + fs;
            ah[i] = *(const bf16x8*)(b + LDS_A_HI + ro);
            al[i] = *(const bf16x8*)(b + LDS_A_LO + ro);
        }
#pragma unroll
        for (int j = 0; j < 4; ++j) {
            int ro = (wn + j * 16 + lr16) * 64 + fs;
            bh[j] = *(const bf16x8*)(b + LDS_B_HI + ro);
            bl[j] = *(const bf16x8*)(b + LDS_B_LO + ro);
        }
#pragma unroll
        for (int i = 0; i < 4; ++i)
#pragma unroll
            for (int j = 0; j < 4; ++j) {
                acc[i][j] = __builtin_amdgcn_mfma_f32_16x16x32_bf16(ah[i], bh[j], acc[i][j], 0, 0, 0);
                acc[i][j] = __builtin_amdgcn_mfma_f32_16x16x32_bf16(ah[i], bl[j], acc[i][j], 0, 0, 0);
                acc[i][j] = __builtin_amdgcn_mfma_f32_16x16x32_bf16(al[i], bh[j], acc[i][j], 0, 0, 0);
            }
        __syncthreads();
    }

    // epilogue: bias + relu, store bf16
    float bcol[4];
#pragma unroll
    for (int j = 0; j < 4; ++j) bcol[j] = bias[bn + wn + j * 16 + lr16];
#pragma unroll
    for (int i = 0; i < 4; ++i) {
#pragma unroll
        for (int r = 0; r < 4; ++r) {
            int m = bm + wm + i * 16 + quad * 4 + r;
            if (m < M) {
#pragma unroll
                for (int j = 0; j < 4; ++j) {
                    float vv = fmaxf(acc[i][j][r] + bcol[j], 0.f);
                    Cb[(size_t)m * N + bn + wn + j * 16 + lr16] = f2bf_rne(vv);
                }
            }
        }
    }
}

// ---------------------------------------------------------------------------
// GEMM for layer 3: N=8, K=768, A packed bf16 pairs.  One wave per row.
// ---------------------------------------------------------------------------
__global__ __launch_bounds__(64) void gemm_n8_kernel(const unsigned int* __restrict__ Apk,
                                                     const float* __restrict__ B,
                                                     float* __restrict__ C) {
    const int m = blockIdx.x;
    const int lane = (int)threadIdx.x;
    const unsigned int* a = Apk + m * 384;   // 384 pairs = 768 feats
    float acc[8] = {};
#pragma unroll
    for (int it = 0; it < 6; ++it) {
        int j2 = lane + it * 64;
        unsigned int av = a[j2];
        float a0 = lo_f(av), a1 = hi_f(av);
        const float* B0 = B + (size_t)(2 * j2) * 8;
        float4 p0 = *(const float4*)(B0);
        float4 p1 = *(const float4*)(B0 + 4);
        float4 q0 = *(const float4*)(B0 + 8);
        float4 q1 = *(const float4*)(B0 + 12);
        acc[0] += a0 * p0.x + a1 * q0.x; acc[1] += a0 * p0.y + a1 * q0.y;
        acc[2] += a0 * p0.z + a1 * q0.z; acc[3] += a0 * p0.w + a1 * q0.w;
        acc[4] += a0 * p1.x + a1 * q1.x; acc[5] += a0 * p1.y + a1 * q1.y;
        acc[6] += a0 * p1.z + a1 * q1.z; acc[7] += a0 * p1.w + a1 * q1.w;
    }
#pragma unroll
    for (int off = 32; off > 0; off >>= 1) {
#pragma unroll
        for (int i = 0; i < 8; ++i) acc[i] += __shfl_down(acc[i], off);
    }
    if (lane == 0) {
#pragma unroll
        for (int i = 0; i < 8; ++i) C[(size_t)m * 8 + i] = acc[i];
    }
}

// Aggregation for fout=8 (final layer, +bias): one wave per node, lanes split edges.
__global__ __launch_bounds__(64) void agg8_kernel(const float* __restrict__ xw,
                                                  const int* __restrict__ ptr,
                                                  const int* __restrict__ csr_src,
                                                  const float* __restrict__ csr_w,
                                                  const float* __restrict__ dinv,
                                                  const float* __restrict__ bias,
                                                  float* __restrict__ out) {
    int node = blockIdx.x;
    int lane = threadIdx.x;
    float acc[8] = {};
    int s = ptr[node], e = ptr[node + 1];
    for (int j = s + lane; j < e; j += 64) {
        int src = csr_src[j];
        float w = csr_w[j];
        float4 g0 = *(const float4*)(xw + (size_t)src * 8);
        float4 g1 = *(const float4*)(xw + (size_t)src * 8 + 4);
        acc[0] += w * g0.x; acc[1] += w * g0.y; acc[2] += w * g0.z; acc[3] += w * g0.w;
        acc[4] += w * g1.x; acc[5] += w * g1.y; acc[6] += w * g1.z; acc[7] += w * g1.w;
    }
#pragma unroll
    for (int off = 32; off > 0; off >>= 1) {
#pragma unroll
        for (int i = 0; i < 8; ++i) acc[i] += __shfl_down(acc[i], off);
    }
    if (lane == 0) {
        float di = dinv[node];
        float si = di * di;
#pragma unroll
        for (int i = 0; i < 8; ++i)
            out[(size_t)node * 8 + i] = acc[i] + si * xw[(size_t)node * 8 + i] + bias[i];
    }
}

// ---------------------------------------------------------------------------

extern "C" void kernel_launch(void* const* d_in, const int* in_sizes, int n_in,
                              void* d_out, int out_size, void* d_ws, size_t ws_size,
                              hipStream_t stream) {
    const int N = N_NODES, E = N_EDGES;
    const int N_PAD = ((N + TM - 1) / TM) * TM;   // 10112
    const float* x   = (const float*)d_in[0];
    const int*   ei  = (const int*)d_in[1];   // [2, E] (row=source, col=target)
    const float* ew  = (const float*)d_in[2];
    const float* W1  = (const float*)d_in[3];
    const float* b1  = (const float*)d_in[4];
    const float* W2  = (const float*)d_in[5];
    const float* b2  = (const float*)d_in[6];
    const float* W3  = (const float*)d_in[7];
    const float* b3  = (const float*)d_in[8];
    float* out = (float*)d_out;

    const int* row = ei;        // source
    const int* col = ei + E;    // target

    // workspace layout (256B-aligned); ~50 MB total
    char* ws = (char*)d_ws;
    size_t off = 0;
    auto alloc = [&](size_t bytes) {
        void* p = ws + off;
        off += (bytes + 255) & ~(size_t)255;
        return p;
    };
    float*          deg     = (float*)alloc((size_t)N * 4);
    float*          dinv    = (float*)alloc((size_t)N * 4);
    int*            counts  = (int*)alloc((size_t)N * 4);
    int*            col_ptr = (int*)alloc((size_t)(N + 1) * 4);
    int*            slot    = (int*)alloc((size_t)E * 4);
    int*            csr_src = (int*)alloc((size_t)E_PAD * 4);
    float*          csr_w   = (float*)alloc((size_t)E_PAD * 4);
    unsigned short* xbf     = (unsigned short*)alloc((size_t)N * 256 * 2);   // x as bf16
    unsigned short* h1bf    = (unsigned short*)alloc((size_t)N * 512 * 2);   // gemm1 out bf16
    unsigned short* h2bf    = (unsigned short*)alloc((size_t)N * 768 * 2);   // gemm2 out bf16
    unsigned short* Ahi     = (unsigned short*)alloc((size_t)N_PAD * 512 * 2);
    unsigned short* Alo     = (unsigned short*)alloc((size_t)N_PAD * 512 * 2);
    unsigned short* W1thi   = (unsigned short*)alloc((size_t)512 * 256 * 2);
    unsigned short* W1tlo   = (unsigned short*)alloc((size_t)512 * 256 * 2);
    unsigned short* W2thi   = (unsigned short*)alloc((size_t)768 * 512 * 2);
    unsigned short* W2tlo   = (unsigned short*)alloc((size_t)768 * 512 * 2);
    float*          xw8     = (float*)alloc((size_t)N * 8 * 4);
    (void)ws_size;

    int nb_edges = (E + 255) / 256;

    // --- fused setup (init + CSR zero + x->bf16 + weight conversion) ---
    {
        int tot = N + E_PAD + N * 256 + 256 * 512 + 512 * 768;
        setup_kernel<<<(tot + 255) / 256, 256, 0, stream>>>(
            deg, counts, csr_src, csr_w, x, xbf,
            W1, W1thi, W1tlo, W2, W2thi, W2tlo);
    }
    count_slot_kernel<<<nb_edges, 256, 0, stream>>>(col, ew, deg, counts, slot, E);
    scan_dinv_kernel<<<1, 1024, 0, stream>>>(counts, col_ptr, deg, dinv, N);
    scatter_kernel<<<nb_edges, 256, 0, stream>>>(row, col, ew, dinv, col_ptr, slot,
                                                 csr_src, csr_w, E);

    // --- layer 1: agg(bf16 x, 2 slices) -> gemm 256->512 (+b1, relu, bf16 out)
    agg_slice_kernel<256, 1><<<N * 2, 64, 0, stream>>>(
        (const unsigned int*)xbf, col_ptr, csr_src, csr_w, dinv,
        (unsigned int*)Ahi, (unsigned int*)Alo);
    {
        dim3 grid(512 / TN, N_PAD / TM);
        gemm_mfma_kernel<<<grid, 256, 0, stream>>>(Ahi, Alo, W1thi, W1tlo, b1,
                                                   h1bf, N, 256, 512);
    }
    // --- layer 2: agg(bf16 h1, 4 slices) -> gemm 512->768 (+b2, relu, bf16 out)
    agg_slice_kernel<512, 2><<<N * 4, 64, 0, stream>>>(
        (const unsigned int*)h1bf, col_ptr, csr_src, csr_w, dinv,
        (unsigned int*)Ahi, (unsigned int*)Alo);
    {
        dim3 grid(768 / TN, N_PAD / TM);
        gemm_mfma_kernel<<<grid, 256, 0, stream>>>(Ahi, Alo, W2thi, W2tlo, b2,
                                                   h2bf, N, 512, 768);
    }
    // --- layer 3: gemm 768->8 (packed bf16 A) -> agg8 (+b3) ---
    gemm_n8_kernel<<<N, 64, 0, stream>>>((const unsigned int*)h2bf, W3, xw8);
    agg8_kernel<<<N, 64, 0, stream>>>(xw8, col_ptr, csr_src, csr_w, dinv, b3, out);

    (void)out_size; (void)n_in; (void)in_sizes;
}